// Round 1
// baseline (203.890 us; speedup 1.0000x reference)
//
#include <hip/hip_runtime.h>
#include <hip/hip_bf16.h>

typedef unsigned short u16;
typedef short s16x8 __attribute__((ext_vector_type(8)));
typedef float f32x4 __attribute__((ext_vector_type(4)));
typedef int i32x4 __attribute__((ext_vector_type(4)));

// fp32 -> bf16 round-to-nearest-even
static __device__ __forceinline__ u16 f2b(float f) {
    union { float f; unsigned u; } x; x.f = f;
    unsigned r = x.u + 0x7fffu + ((x.u >> 16) & 1u);
    return (u16)(r >> 16);
}

// ---------------- stage 0: packing / conversion ----------------

__global__ void k_cvt_x(const float* __restrict__ x, u16* __restrict__ xb) {
    int i = (blockIdx.x * 256 + threadIdx.x) * 4;
    float4 v = *(const float4*)(x + i);
    ushort4 o;
    o.x = f2b(v.x); o.y = f2b(v.y); o.z = f2b(v.z); o.w = f2b(v.w);
    *(ushort4*)(xb + i) = o;
}

// W [H=8][D=512][E=64] fp32 -> WT [(h*64+e)=512][512] bf16
__global__ void k_pack_w(const float* __restrict__ W, u16* __restrict__ WT) {
    int idx = blockIdx.x * 256 + threadIdx.x;   // 0..262143
    int n = idx >> 9, d = idx & 511;
    WT[idx] = f2b(W[((n >> 6) * 512 + d) * 64 + (n & 63)]);
}

// Wo [512][512] -> WoT [col][d]
__global__ void k_pack_wo(const float* __restrict__ W, u16* __restrict__ WT) {
    int idx = blockIdx.x * 256 + threadIdx.x;
    int n = idx >> 9, d = idx & 511;
    WT[idx] = f2b(W[d * 512 + n]);
}

__global__ void k_pack_bias(const float* __restrict__ bq, const float* __restrict__ bk,
                            const float* __restrict__ bv, const float* __restrict__ bo,
                            float* __restrict__ out) {
    int i = blockIdx.x * 256 + threadIdx.x;     // 0..2047
    float v;
    if (i < 512) v = bq[i];
    else if (i < 1024) v = bk[i - 512];
    else if (i < 1536) v = bv[i - 1024];
    else v = bo[i - 1536];
    out[i] = v;
}

// ---------------- GEMM: C[4096,512] = A[4096,512] * BT[512,512]^T + bias ----------------
// BM=128 BN=128 BK=64, 256 threads (4 waves, 2x2 of 64x64). LDS XOR-swizzled.

template<bool F32OUT>
__global__ __launch_bounds__(256)
void k_gemm(const u16* __restrict__ A, const u16* __restrict__ BTbase,
            const float* __restrict__ biasBase,
            u16* __restrict__ Cb, float* __restrict__ Cf) {
    const int nblk = blockIdx.x, mblk = blockIdx.y, z = blockIdx.z;
    const u16* BT = BTbase + (size_t)z * 262144;
    const float* bias = biasBase + z * 512;
    __shared__ __align__(16) u16 As[128 * 64];
    __shared__ __align__(16) u16 Bs[128 * 64];
    const int tid = threadIdx.x, lane = tid & 63, wv = tid >> 6;
    const int lr = lane & 15, lg = lane >> 4;
    const int wr = (wv >> 1) * 64, wc = (wv & 1) * 64;
    const u16* Ag = A + (size_t)(mblk * 128) * 512;
    const u16* Bg = BT + (size_t)(nblk * 128) * 512;

    f32x4 acc[4][4];
#pragma unroll
    for (int i = 0; i < 4; i++)
#pragma unroll
        for (int j = 0; j < 4; j++) acc[i][j] = (f32x4){0.f, 0.f, 0.f, 0.f};

    for (int kt = 0; kt < 8; kt++) {
        __syncthreads();
#pragma unroll
        for (int i = 0; i < 4; i++) {
            int f = i * 256 + tid, r = f >> 3, c = f & 7;
            *(i32x4*)&As[r * 64 + ((c * 8) ^ ((r & 7) << 3))] =
                *(const i32x4*)(Ag + (size_t)r * 512 + kt * 64 + c * 8);
            *(i32x4*)&Bs[r * 64 + ((c * 8) ^ ((r & 7) << 3))] =
                *(const i32x4*)(Bg + (size_t)r * 512 + kt * 64 + c * 8);
        }
        __syncthreads();
#pragma unroll
        for (int ks = 0; ks < 2; ks++) {
            s16x8 af[4], bf[4];
#pragma unroll
            for (int mf = 0; mf < 4; mf++) {
                int r = wr + mf * 16 + lr;
                af[mf] = *(const s16x8*)&As[r * 64 + ((ks * 32 + lg * 8) ^ ((r & 7) << 3))];
            }
#pragma unroll
            for (int nf = 0; nf < 4; nf++) {
                int r = wc + nf * 16 + lr;
                bf[nf] = *(const s16x8*)&Bs[r * 64 + ((ks * 32 + lg * 8) ^ ((r & 7) << 3))];
            }
#pragma unroll
            for (int mf = 0; mf < 4; mf++)
#pragma unroll
                for (int nf = 0; nf < 4; nf++)
                    acc[mf][nf] = __builtin_amdgcn_mfma_f32_16x16x32_bf16(
                        af[mf], bf[nf], acc[mf][nf], 0, 0, 0);
        }
    }
#pragma unroll
    for (int nf = 0; nf < 4; nf++) {
        int col = nblk * 128 + wc + nf * 16 + lr;
        float bval = bias[col];
#pragma unroll
        for (int mf = 0; mf < 4; mf++) {
#pragma unroll
            for (int r = 0; r < 4; r++) {
                int row = mblk * 128 + wr + mf * 16 + lg * 4 + r;
                float v = acc[mf][nf][r] + bval;
                if (F32OUT) Cf[(size_t)row * 512 + col] = v;
                else        Cb[(size_t)z * 2097152 + (size_t)row * 512 + col] = f2b(v);
            }
        }
    }
}

// ---------------- flash attention ----------------
// grid (qt=16, h=8, b=2), 512 threads = 8 waves, wave owns 16 q-rows, KV tile 128.

__global__ __launch_bounds__(512)
void k_attn(const u16* __restrict__ qkv, const int* __restrict__ mask,
            u16* __restrict__ oc) {
    const int qt = blockIdx.x, h = blockIdx.y, b = blockIdx.z;
    const u16* Q = qkv + (size_t)b * 1048576 + h * 64;
    const u16* K = Q + 2097152;
    const u16* V = K + 2097152;
    __shared__ __align__(16) u16 KsB[8192];     // [128][64] swizzled
    __shared__ __align__(16) u16 VtB[8192];     // [64][128] transposed+swizzled; doubles as Qs
    __shared__ __align__(16) u16 Ps[8][2048];   // per-wave [16][128] swizzled
    const int tid = threadIdx.x, lane = tid & 63, wv = tid >> 6;
    const int lr = lane & 15, lg = lane >> 4;
    u16* Qs = VtB;

    // Q tile [128][64] -> LDS (swizzled), then fragments to registers
#pragma unroll
    for (int i = 0; i < 2; i++) {
        int f = i * 512 + tid, r = f >> 3, c = f & 7;
        *(i32x4*)&Qs[r * 64 + ((c * 8) ^ ((r & 7) << 3))] =
            *(const i32x4*)(Q + (size_t)(qt * 128 + r) * 512 + c * 8);
    }
    __syncthreads();
    s16x8 qf[2];
#pragma unroll
    for (int ks = 0; ks < 2; ks++) {
        int r = wv * 16 + lr;
        qf[ks] = *(const s16x8*)&Qs[r * 64 + ((ks * 32 + lg * 8) ^ ((r & 7) << 3))];
    }

    f32x4 accO[4];
#pragma unroll
    for (int i = 0; i < 4; i++) accO[i] = (f32x4){0.f, 0.f, 0.f, 0.f};
    float mrow[4], lrow[4];
#pragma unroll
    for (int r = 0; r < 4; r++) { mrow[r] = -INFINITY; lrow[r] = 0.f; }

    const float SC = 0.18033688011112042f;      // (1/8) * log2(e)
    const float MB = -1.4426950e9f;             // -1e9 * log2(e)
    u16* Pw = &Ps[wv][0];
    const int* Mrow = mask + ((size_t)b * 2048 + qt * 128 + wv * 16 + lg * 4) * 2048;

    for (int t = 0; t < 16; t++) {
        __syncthreads();
        // stage K [128][64] swizzled
#pragma unroll
        for (int i = 0; i < 2; i++) {
            int f = i * 512 + tid, r = f >> 3, c = f & 7;
            *(i32x4*)&KsB[r * 64 + ((c * 8) ^ ((r & 7) << 3))] =
                *(const i32x4*)(K + (size_t)(t * 128 + r) * 512 + c * 8);
        }
        // stage V transposed: VtB[e][kv], idx = e*128 + (kv ^ ((e&7)<<3)), rotated writes
#pragma unroll
        for (int i = 0; i < 2; i++) {
            int f = i * 512 + tid, r = f >> 3, c = f & 7;
            union { i32x4 v; u16 u[8]; } uu;
            uu.v = *(const i32x4*)(V + (size_t)(t * 128 + r) * 512 + c * 8);
#pragma unroll
            for (int jj = 0; jj < 8; jj++) {
                int j = (jj + c) & 7;
                int e = c * 8 + j;
                VtB[e * 128 + (r ^ (j << 3))] = uu.u[j];
            }
        }
        __syncthreads();

        // scores: S[16 q][128 kv] per wave
        f32x4 s[8];
#pragma unroll
        for (int nf = 0; nf < 8; nf++) s[nf] = (f32x4){0.f, 0.f, 0.f, 0.f};
#pragma unroll
        for (int ks = 0; ks < 2; ks++) {
#pragma unroll
            for (int nf = 0; nf < 8; nf++) {
                int r = nf * 16 + lr;
                s16x8 kf = *(const s16x8*)&KsB[r * 64 + ((ks * 32 + lg * 8) ^ ((r & 7) << 3))];
                s[nf] = __builtin_amdgcn_mfma_f32_16x16x32_bf16(qf[ks], kf, s[nf], 0, 0, 0);
            }
        }
        // scale + mask in log2 domain
#pragma unroll
        for (int nf = 0; nf < 8; nf++) {
#pragma unroll
            for (int r = 0; r < 4; r++) {
                float mv = (float)Mrow[r * 2048 + t * 128 + nf * 16 + lr];
                s[nf][r] = s[nf][r] * SC + mv * MB;
            }
        }
        // row max (in-lane over 8 col-frags, then across 16 lanes)
        float rsc[4];
#pragma unroll
        for (int r = 0; r < 4; r++) {
            float v = s[0][r];
#pragma unroll
            for (int nf = 1; nf < 8; nf++) v = fmaxf(v, s[nf][r]);
#pragma unroll
            for (int msk = 1; msk < 16; msk <<= 1) v = fmaxf(v, __shfl_xor(v, msk));
            float mn = fmaxf(mrow[r], v);
            rsc[r] = exp2f(mrow[r] - mn);
            mrow[r] = mn;
        }
        // p = exp2(s - m): write bf16 P to LDS, accumulate row sums
        float rs[4] = {0.f, 0.f, 0.f, 0.f};
#pragma unroll
        for (int nf = 0; nf < 8; nf++) {
#pragma unroll
            for (int r = 0; r < 4; r++) {
                float p = exp2f(s[nf][r] - mrow[r]);
                rs[r] += p;
                int m = lg * 4 + r;
                Pw[m * 128 + ((nf * 16 + lr) ^ ((m & 7) << 3))] = f2b(p);
            }
        }
#pragma unroll
        for (int r = 0; r < 4; r++) {
#pragma unroll
            for (int msk = 1; msk < 16; msk <<= 1) rs[r] += __shfl_xor(rs[r], msk);
            lrow[r] = lrow[r] * rsc[r] + rs[r];
        }
        // rescale O
#pragma unroll
        for (int nf = 0; nf < 4; nf++)
#pragma unroll
            for (int r = 0; r < 4; r++) accO[nf][r] *= rsc[r];
        // PV: O[16 q][64 e] += P[16][128] * V[128][64]
#pragma unroll
        for (int ks = 0; ks < 4; ks++) {
            s16x8 pf = *(const s16x8*)&Pw[lr * 128 + ((ks * 32 + lg * 8) ^ ((lr & 7) << 3))];
#pragma unroll
            for (int nf = 0; nf < 4; nf++) {
                int e = nf * 16 + lr;
                s16x8 vf = *(const s16x8*)&VtB[e * 128 + ((ks * 32 + lg * 8) ^ ((e & 7) << 3))];
                accO[nf] = __builtin_amdgcn_mfma_f32_16x16x32_bf16(pf, vf, accO[nf], 0, 0, 0);
            }
        }
    }
    // epilogue: O/l -> oc[b][s][h*64+e] bf16
#pragma unroll
    for (int nf = 0; nf < 4; nf++) {
#pragma unroll
        for (int r = 0; r < 4; r++) {
            int row = qt * 128 + wv * 16 + lg * 4 + r;
            float v = accO[nf][r] / lrow[r];
            oc[(size_t)(b * 2048 + row) * 512 + h * 64 + nf * 16 + lr] = f2b(v);
        }
    }
}

// ---------------- launcher ----------------

extern "C" void kernel_launch(void* const* d_in, const int* in_sizes, int n_in,
                              void* d_out, int out_size, void* d_ws, size_t ws_size,
                              hipStream_t stream) {
    const float* x    = (const float*)d_in[0];
    const int*   mask = (const int*)d_in[1];
    const float* Wq   = (const float*)d_in[2];
    const float* bq   = (const float*)d_in[3];
    const float* Wk   = (const float*)d_in[4];
    const float* bk   = (const float*)d_in[5];
    const float* Wv   = (const float*)d_in[6];
    const float* bv   = (const float*)d_in[7];
    const float* Wo   = (const float*)d_in[8];
    const float* bo   = (const float*)d_in[9];

    u16* xb     = (u16*)d_ws;              // 2097152 bf16
    u16* WT     = xb + 2097152;            // 3*262144
    u16* WoT    = WT + 786432;             // 262144
    u16* qkv    = WoT + 262144;            // 3*2097152
    u16* oc     = qkv + 6291456;           // 2097152
    float* bias = (float*)(oc + 2097152);  // 2048 floats

    k_cvt_x   <<<2048, 256, 0, stream>>>(x, xb);
    k_pack_w  <<<1024, 256, 0, stream>>>(Wq, WT);
    k_pack_w  <<<1024, 256, 0, stream>>>(Wk, WT + 262144);
    k_pack_w  <<<1024, 256, 0, stream>>>(Wv, WT + 524288);
    k_pack_wo <<<1024, 256, 0, stream>>>(Wo, WoT);
    k_pack_bias<<<8, 256, 0, stream>>>(bq, bk, bv, bo, bias);

    k_gemm<false><<<dim3(4, 32, 3), 256, 0, stream>>>(xb, WT, bias, qkv, nullptr);
    k_attn<<<dim3(16, 8, 2), 512, 0, stream>>>(qkv, mask, oc);
    k_gemm<true><<<dim3(4, 32, 1), 256, 0, stream>>>(oc, WoT, bias + 1536, nullptr, (float*)d_out);
}

// Round 2
// 142.570 us; speedup vs baseline: 1.4301x; 1.4301x over previous
//
#include <hip/hip_runtime.h>
#include <hip/hip_bf16.h>

typedef unsigned short u16;
typedef short s16x8 __attribute__((ext_vector_type(8)));
typedef float f32x4 __attribute__((ext_vector_type(4)));
typedef int i32x4 __attribute__((ext_vector_type(4)));

// fp32 -> bf16 round-to-nearest-even
static __device__ __forceinline__ u16 f2b(float f) {
    union { float f; unsigned u; } x; x.f = f;
    unsigned r = x.u + 0x7fffu + ((x.u >> 16) & 1u);
    return (u16)(r >> 16);
}

// ---------------- stage 0: packing / conversion ----------------

__global__ void k_cvt_x(const float* __restrict__ x, u16* __restrict__ xb) {
    int i = (blockIdx.x * 256 + threadIdx.x) * 4;
    float4 v = *(const float4*)(x + i);
    ushort4 o;
    o.x = f2b(v.x); o.y = f2b(v.y); o.z = f2b(v.z); o.w = f2b(v.w);
    *(ushort4*)(xb + i) = o;
}

// W [H=8][D=512][E=64] fp32 -> WT [(h*64+e)=512][512] bf16
__global__ void k_pack_w(const float* __restrict__ W, u16* __restrict__ WT) {
    int idx = blockIdx.x * 256 + threadIdx.x;   // 0..262143
    int n = idx >> 9, d = idx & 511;
    WT[idx] = f2b(W[((n >> 6) * 512 + d) * 64 + (n & 63)]);
}

// Wo [512][512] -> WoT [col][d]
__global__ void k_pack_wo(const float* __restrict__ W, u16* __restrict__ WT) {
    int idx = blockIdx.x * 256 + threadIdx.x;
    int n = idx >> 9, d = idx & 511;
    WT[idx] = f2b(W[d * 512 + n]);
}

__global__ void k_pack_bias(const float* __restrict__ bq, const float* __restrict__ bk,
                            const float* __restrict__ bv, const float* __restrict__ bo,
                            float* __restrict__ out) {
    int i = blockIdx.x * 256 + threadIdx.x;     // 0..2047
    float v;
    if (i < 512) v = bq[i];
    else if (i < 1024) v = bk[i - 512];
    else if (i < 1536) v = bv[i - 1024];
    else v = bo[i - 1536];
    out[i] = v;
}

// mask [2][2048][2048] int32 (0/1) -> bits, 32 cols per word: mb[(b*2048+s)*64 + c32]
__global__ void k_pack_mbits(const int* __restrict__ mask, unsigned* __restrict__ mb) {
    int idx = blockIdx.x * 256 + threadIdx.x;   // 0..262143, each covers 32 ints
    const int* p = mask + (size_t)idx * 32;
    unsigned w = 0;
#pragma unroll
    for (int j = 0; j < 32; j += 4) {
        int4 v = *(const int4*)(p + j);
        w |= ((unsigned)(v.x & 1) << j) | ((unsigned)(v.y & 1) << (j + 1)) |
             ((unsigned)(v.z & 1) << (j + 2)) | ((unsigned)(v.w & 1) << (j + 3));
    }
    mb[idx] = w;
}

// ---------------- GEMM: C[4096,512] = A[4096,512] * BT[512,512]^T + bias ----------------

template<bool F32OUT>
__global__ __launch_bounds__(256)
void k_gemm(const u16* __restrict__ A, const u16* __restrict__ BTbase,
            const float* __restrict__ biasBase,
            u16* __restrict__ Cb, float* __restrict__ Cf) {
    const int nblk = blockIdx.x, mblk = blockIdx.y, z = blockIdx.z;
    const u16* BT = BTbase + (size_t)z * 262144;
    const float* bias = biasBase + z * 512;
    __shared__ __align__(16) u16 As[128 * 64];
    __shared__ __align__(16) u16 Bs[128 * 64];
    const int tid = threadIdx.x, lane = tid & 63, wv = tid >> 6;
    const int lr = lane & 15, lg = lane >> 4;
    const int wr = (wv >> 1) * 64, wc = (wv & 1) * 64;
    const u16* Ag = A + (size_t)(mblk * 128) * 512;
    const u16* Bg = BT + (size_t)(nblk * 128) * 512;

    f32x4 acc[4][4];
#pragma unroll
    for (int i = 0; i < 4; i++)
#pragma unroll
        for (int j = 0; j < 4; j++) acc[i][j] = (f32x4){0.f, 0.f, 0.f, 0.f};

    for (int kt = 0; kt < 8; kt++) {
        __syncthreads();
#pragma unroll
        for (int i = 0; i < 4; i++) {
            int f = i * 256 + tid, r = f >> 3, c = f & 7;
            *(i32x4*)&As[r * 64 + ((c * 8) ^ ((r & 7) << 3))] =
                *(const i32x4*)(Ag + (size_t)r * 512 + kt * 64 + c * 8);
            *(i32x4*)&Bs[r * 64 + ((c * 8) ^ ((r & 7) << 3))] =
                *(const i32x4*)(Bg + (size_t)r * 512 + kt * 64 + c * 8);
        }
        __syncthreads();
#pragma unroll
        for (int ks = 0; ks < 2; ks++) {
            s16x8 af[4], bf[4];
#pragma unroll
            for (int mf = 0; mf < 4; mf++) {
                int r = wr + mf * 16 + lr;
                af[mf] = *(const s16x8*)&As[r * 64 + ((ks * 32 + lg * 8) ^ ((r & 7) << 3))];
            }
#pragma unroll
            for (int nf = 0; nf < 4; nf++) {
                int r = wc + nf * 16 + lr;
                bf[nf] = *(const s16x8*)&Bs[r * 64 + ((ks * 32 + lg * 8) ^ ((r & 7) << 3))];
            }
#pragma unroll
            for (int mf = 0; mf < 4; mf++)
#pragma unroll
                for (int nf = 0; nf < 4; nf++)
                    acc[mf][nf] = __builtin_amdgcn_mfma_f32_16x16x32_bf16(
                        af[mf], bf[nf], acc[mf][nf], 0, 0, 0);
        }
    }
#pragma unroll
    for (int nf = 0; nf < 4; nf++) {
        int col = nblk * 128 + wc + nf * 16 + lr;
        float bval = bias[col];
#pragma unroll
        for (int mf = 0; mf < 4; mf++) {
#pragma unroll
            for (int r = 0; r < 4; r++) {
                int row = mblk * 128 + wr + mf * 16 + lg * 4 + r;
                float v = acc[mf][nf][r] + bval;
                if (F32OUT) Cf[(size_t)row * 512 + col] = v;
                else        Cb[(size_t)z * 2097152 + (size_t)row * 512 + col] = f2b(v);
            }
        }
    }
}

// ---------------- flash attention ----------------
// grid (qt=16, h=8, b=2), 512 threads = 8 waves, wave owns 16 q-rows, KV tile 128.
// Double-buffered K/Vt LDS; tile t+1 global loads issued into registers before
// compute(t) (latency hidden under compute); ds_writes after the barrier.
// Mask comes from bit-packed mb (4x dwordx4 per lane per tile, L1/L2-hot).

__global__ __launch_bounds__(512)
void k_attn(const u16* __restrict__ qkv, const uint4* __restrict__ mbits,
            u16* __restrict__ oc) {
    const int qt = blockIdx.x, h = blockIdx.y, b = blockIdx.z;
    const u16* Q = qkv + (size_t)b * 1048576 + h * 64;
    const u16* K = Q + 2097152;
    const u16* V = K + 2097152;
    __shared__ __align__(16) u16 Ks[2][8192];   // [128][64] swizzled, dbuf
    __shared__ __align__(16) u16 Vt[2][8192];   // [64][128] transposed+swizzled, dbuf
    __shared__ __align__(16) u16 Ps[8][2048];   // per-wave [16][128] swizzled
    const int tid = threadIdx.x, lane = tid & 63, wv = tid >> 6;
    const int lr = lane & 15, lg = lane >> 4;

    // Q tile [128][64] -> LDS (alias Ks[0], swizzled) -> register fragments
    u16* Qs = &Ks[0][0];
#pragma unroll
    for (int i = 0; i < 2; i++) {
        int f = i * 512 + tid, r = f >> 3, c = f & 7;
        *(i32x4*)&Qs[r * 64 + ((c * 8) ^ ((r & 7) << 3))] =
            *(const i32x4*)(Q + (size_t)(qt * 128 + r) * 512 + c * 8);
    }
    __syncthreads();
    s16x8 qf[2];
#pragma unroll
    for (int ks = 0; ks < 2; ks++) {
        int r = wv * 16 + lr;
        qf[ks] = *(const s16x8*)&Qs[r * 64 + ((ks * 32 + lg * 8) ^ ((r & 7) << 3))];
    }
    __syncthreads();

    // prologue: stage tile 0 into buffer 0, load mask bits for tile 0
#pragma unroll
    for (int i = 0; i < 2; i++) {
        int f = i * 512 + tid, r = f >> 3, c = f & 7;
        *(i32x4*)&Ks[0][r * 64 + ((c * 8) ^ ((r & 7) << 3))] =
            *(const i32x4*)(K + (size_t)r * 512 + c * 8);
        union { i32x4 v; u16 u[8]; } uu;
        uu.v = *(const i32x4*)(V + (size_t)r * 512 + c * 8);
#pragma unroll
        for (int jj = 0; jj < 8; jj++) {
            int j = (jj + c) & 7, e = c * 8 + j;
            Vt[0][e * 128 + (r ^ (j << 3))] = uu.u[j];
        }
    }
    const size_t mrb = ((size_t)b * 2048 + qt * 128 + wv * 16 + lg * 4) * 16;
    uint4 mreg[4];
#pragma unroll
    for (int r = 0; r < 4; r++) mreg[r] = mbits[mrb + (size_t)r * 16];
    __syncthreads();

    f32x4 accO[4];
#pragma unroll
    for (int i = 0; i < 4; i++) accO[i] = (f32x4){0.f, 0.f, 0.f, 0.f};
    float mrow[4], lrow[4];
#pragma unroll
    for (int r = 0; r < 4; r++) { mrow[r] = -INFINITY; lrow[r] = 0.f; }

    const float SC = 0.18033688011112042f;      // (1/8) * log2(e)
    const float MB = -1.4426950e9f;             // -1e9 * log2(e)
    u16* Pw = &Ps[wv][0];

    for (int t = 0; t < 16; t++) {
        const int cur = t & 1, nxt = cur ^ 1;
        // ---- issue prefetch for tile t+1 into registers (no wait yet) ----
        i32x4 kreg[2], vreg[2];
        uint4 mnext[4];
        if (t < 15) {
#pragma unroll
            for (int i = 0; i < 2; i++) {
                int f = i * 512 + tid, r = f >> 3, c = f & 7;
                kreg[i] = *(const i32x4*)(K + (size_t)((t + 1) * 128 + r) * 512 + c * 8);
                vreg[i] = *(const i32x4*)(V + (size_t)((t + 1) * 128 + r) * 512 + c * 8);
            }
#pragma unroll
            for (int r = 0; r < 4; r++) mnext[r] = mbits[mrb + (size_t)r * 16 + t + 1];
        }

        // ---- compute tile t ----
        f32x4 s[8];
#pragma unroll
        for (int nf = 0; nf < 8; nf++) s[nf] = (f32x4){0.f, 0.f, 0.f, 0.f};
#pragma unroll
        for (int ks = 0; ks < 2; ks++) {
#pragma unroll
            for (int nf = 0; nf < 8; nf++) {
                int r = nf * 16 + lr;
                s16x8 kf = *(const s16x8*)&Ks[cur][r * 64 + ((ks * 32 + lg * 8) ^ ((r & 7) << 3))];
                s[nf] = __builtin_amdgcn_mfma_f32_16x16x32_bf16(qf[ks], kf, s[nf], 0, 0, 0);
            }
        }
        // scale + mask (bit-packed) in log2 domain
#pragma unroll
        for (int r = 0; r < 4; r++) {
            unsigned ws_[4] = {mreg[r].x, mreg[r].y, mreg[r].z, mreg[r].w};
#pragma unroll
            for (int nf = 0; nf < 8; nf++) {
                float mv = (float)((ws_[nf >> 1] >> (((nf & 1) << 4) + lr)) & 1u);
                s[nf][r] = s[nf][r] * SC + mv * MB;
            }
        }
        // row max
        float rsc[4];
#pragma unroll
        for (int r = 0; r < 4; r++) {
            float v = s[0][r];
#pragma unroll
            for (int nf = 1; nf < 8; nf++) v = fmaxf(v, s[nf][r]);
#pragma unroll
            for (int msk = 1; msk < 16; msk <<= 1) v = fmaxf(v, __shfl_xor(v, msk));
            float mn = fmaxf(mrow[r], v);
            rsc[r] = exp2f(mrow[r] - mn);
            mrow[r] = mn;
        }
        // p = exp2(s - m): bf16 P to LDS, accumulate row sums
        float rs[4] = {0.f, 0.f, 0.f, 0.f};
#pragma unroll
        for (int nf = 0; nf < 8; nf++) {
#pragma unroll
            for (int r = 0; r < 4; r++) {
                float p = exp2f(s[nf][r] - mrow[r]);
                rs[r] += p;
                int m = lg * 4 + r;
                Pw[m * 128 + ((nf * 16 + lr) ^ ((m & 7) << 3))] = f2b(p);
            }
        }
#pragma unroll
        for (int r = 0; r < 4; r++) {
#pragma unroll
            for (int msk = 1; msk < 16; msk <<= 1) rs[r] += __shfl_xor(rs[r], msk);
            lrow[r] = lrow[r] * rsc[r] + rs[r];
        }
#pragma unroll
        for (int nf = 0; nf < 4; nf++)
#pragma unroll
            for (int r = 0; r < 4; r++) accO[nf][r] *= rsc[r];
        // PV: O[16 q][64 e] += P[16][128] * V[128][64]
#pragma unroll
        for (int ks = 0; ks < 4; ks++) {
            s16x8 pf = *(const s16x8*)&Pw[lr * 128 + ((ks * 32 + lg * 8) ^ ((lr & 7) << 3))];
#pragma unroll
            for (int nf = 0; nf < 4; nf++) {
                int e = nf * 16 + lr;
                s16x8 vf = *(const s16x8*)&Vt[cur][e * 128 + ((ks * 32 + lg * 8) ^ ((e & 7) << 3))];
                accO[nf] = __builtin_amdgcn_mfma_f32_16x16x32_bf16(pf, vf, accO[nf], 0, 0, 0);
            }
        }

        // ---- write prefetched tile t+1 into the other buffer ----
        __syncthreads();
        if (t < 15) {
#pragma unroll
            for (int i = 0; i < 2; i++) {
                int f = i * 512 + tid, r = f >> 3, c = f & 7;
                *(i32x4*)&Ks[nxt][r * 64 + ((c * 8) ^ ((r & 7) << 3))] = kreg[i];
                union { i32x4 v; u16 u[8]; } uu;
                uu.v = vreg[i];
#pragma unroll
                for (int jj = 0; jj < 8; jj++) {
                    int j = (jj + c) & 7, e = c * 8 + j;
                    Vt[nxt][e * 128 + (r ^ (j << 3))] = uu.u[j];
                }
            }
#pragma unroll
            for (int r = 0; r < 4; r++) mreg[r] = mnext[r];
        }
        __syncthreads();
    }

    // epilogue: O/l -> oc[b][s][h*64+e] bf16
#pragma unroll
    for (int nf = 0; nf < 4; nf++) {
#pragma unroll
        for (int r = 0; r < 4; r++) {
            int row = qt * 128 + wv * 16 + lg * 4 + r;
            float v = accO[nf][r] / lrow[r];
            oc[(size_t)(b * 2048 + row) * 512 + h * 64 + nf * 16 + lr] = f2b(v);
        }
    }
}

// ---------------- launcher ----------------

extern "C" void kernel_launch(void* const* d_in, const int* in_sizes, int n_in,
                              void* d_out, int out_size, void* d_ws, size_t ws_size,
                              hipStream_t stream) {
    const float* x    = (const float*)d_in[0];
    const int*   mask = (const int*)d_in[1];
    const float* Wq   = (const float*)d_in[2];
    const float* bq   = (const float*)d_in[3];
    const float* Wk   = (const float*)d_in[4];
    const float* bk   = (const float*)d_in[5];
    const float* Wv   = (const float*)d_in[6];
    const float* bv   = (const float*)d_in[7];
    const float* Wo   = (const float*)d_in[8];
    const float* bo   = (const float*)d_in[9];

    u16* xb     = (u16*)d_ws;              // 2097152 bf16
    u16* WT     = xb + 2097152;            // 3*262144
    u16* WoT    = WT + 786432;             // 262144
    u16* qkv    = WoT + 262144;            // 3*2097152
    u16* oc     = qkv + 6291456;           // 2097152
    float* bias = (float*)(oc + 2097152);  // 2048 floats
    unsigned* mb = (unsigned*)(bias + 2048); // 262144 words (1 MB)

    k_cvt_x     <<<2048, 256, 0, stream>>>(x, xb);
    k_pack_w    <<<1024, 256, 0, stream>>>(Wq, WT);
    k_pack_w    <<<1024, 256, 0, stream>>>(Wk, WT + 262144);
    k_pack_w    <<<1024, 256, 0, stream>>>(Wv, WT + 524288);
    k_pack_wo   <<<1024, 256, 0, stream>>>(Wo, WoT);
    k_pack_bias <<<8, 256, 0, stream>>>(bq, bk, bv, bo, bias);
    k_pack_mbits<<<1024, 256, 0, stream>>>(mask, mb);

    k_gemm<false><<<dim3(4, 32, 3), 256, 0, stream>>>(xb, WT, bias, qkv, nullptr);
    k_attn<<<dim3(16, 8, 2), 512, 0, stream>>>(qkv, (const uint4*)mb, oc);
    k_gemm<true><<<dim3(4, 32, 1), 256, 0, stream>>>(oc, WoT, bias + 1536, nullptr, (float*)d_out);
}

// Round 5
// 104.589 us; speedup vs baseline: 1.9494x; 1.3631x over previous
//
#include <hip/hip_runtime.h>
#include <hip/hip_bf16.h>

typedef unsigned short u16;
typedef unsigned int u32;
typedef unsigned long long u64;
typedef short s16x8 __attribute__((ext_vector_type(8)));
typedef float f32x4 __attribute__((ext_vector_type(4)));
typedef float f32x16 __attribute__((ext_vector_type(16)));
typedef int i32x4 __attribute__((ext_vector_type(4)));

// fp32 -> bf16 round-to-nearest-even
static __device__ __forceinline__ u16 f2b(float f) {
    union { float f; unsigned u; } x; x.f = f;
    unsigned r = x.u + 0x7fffu + ((x.u >> 16) & 1u);
    return (u16)(r >> 16);
}

static __device__ __forceinline__ f32x16 zero16() {
    f32x16 z;
#pragma unroll
    for (int i = 0; i < 16; i++) z[i] = 0.f;
    return z;
}

static __device__ __forceinline__ s16x8 mk8(u32 a, u32 b, u32 c, u32 d) {
    union { u32 u[4]; s16x8 v; } x;
    x.u[0] = a; x.u[1] = b; x.u[2] = c; x.u[3] = d;
    return x.v;
}

static __device__ __forceinline__ u32 sx32(u32 v) {
    return (u32)__shfl_xor((int)v, 32, 64);
}

// ---------------- stage 0: packing / conversion ----------------

__global__ void k_cvt_x(const float* __restrict__ x, u16* __restrict__ xb) {
    int i = (blockIdx.x * 256 + threadIdx.x) * 4;
    float4 v = *(const float4*)(x + i);
    ushort4 o;
    o.x = f2b(v.x); o.y = f2b(v.y); o.z = f2b(v.z); o.w = f2b(v.w);
    *(ushort4*)(xb + i) = o;
}

// W [H=8][D=512][E=64] fp32 -> WT [(h*64+e)=512][512] bf16
__global__ void k_pack_w(const float* __restrict__ W, u16* __restrict__ WT) {
    int idx = blockIdx.x * 256 + threadIdx.x;
    int n = idx >> 9, d = idx & 511;
    WT[idx] = f2b(W[((n >> 6) * 512 + d) * 64 + (n & 63)]);
}

__global__ void k_pack_wo(const float* __restrict__ W, u16* __restrict__ WT) {
    int idx = blockIdx.x * 256 + threadIdx.x;
    int n = idx >> 9, d = idx & 511;
    WT[idx] = f2b(W[d * 512 + n]);
}

__global__ void k_pack_bias(const float* __restrict__ bq, const float* __restrict__ bk,
                            const float* __restrict__ bv, const float* __restrict__ bo,
                            float* __restrict__ out) {
    int i = blockIdx.x * 256 + threadIdx.x;
    float v;
    if (i < 512) v = bq[i];
    else if (i < 1024) v = bk[i - 512];
    else if (i < 1536) v = bv[i - 1024];
    else v = bo[i - 1536];
    out[i] = v;
}

// mask [2][2048][2048] int32 (0/1) -> bits: mb[(b*2048+s)*64 + c32]
__global__ void k_pack_mbits(const int* __restrict__ mask, unsigned* __restrict__ mb) {
    int idx = blockIdx.x * 256 + threadIdx.x;
    const int* p = mask + (size_t)idx * 32;
    unsigned w = 0;
#pragma unroll
    for (int j = 0; j < 32; j += 4) {
        int4 v = *(const int4*)(p + j);
        w |= ((unsigned)(v.x & 1) << j) | ((unsigned)(v.y & 1) << (j + 1)) |
             ((unsigned)(v.z & 1) << (j + 2)) | ((unsigned)(v.w & 1) << (j + 3));
    }
    mb[idx] = w;
}

// ---------------- GEMM: C[4096,512] = A[4096,512] * BT[512,512]^T + bias ----------------

template<bool F32OUT>
__global__ __launch_bounds__(256)
void k_gemm(const u16* __restrict__ A, const u16* __restrict__ BTbase,
            const float* __restrict__ biasBase,
            u16* __restrict__ Cb, float* __restrict__ Cf) {
    const int nblk = blockIdx.x, mblk = blockIdx.y, z = blockIdx.z;
    const u16* BT = BTbase + (size_t)z * 262144;
    const float* bias = biasBase + z * 512;
    __shared__ __align__(16) u16 As[128 * 64];
    __shared__ __align__(16) u16 Bs[128 * 64];
    const int tid = threadIdx.x, lane = tid & 63, wv = tid >> 6;
    const int lr = lane & 15, lg = lane >> 4;
    const int wr = (wv >> 1) * 64, wc = (wv & 1) * 64;
    const u16* Ag = A + (size_t)(mblk * 128) * 512;
    const u16* Bg = BT + (size_t)(nblk * 128) * 512;

    f32x4 acc[4][4];
#pragma unroll
    for (int i = 0; i < 4; i++)
#pragma unroll
        for (int j = 0; j < 4; j++) acc[i][j] = (f32x4){0.f, 0.f, 0.f, 0.f};

    for (int kt = 0; kt < 8; kt++) {
        __syncthreads();
#pragma unroll
        for (int i = 0; i < 4; i++) {
            int f = i * 256 + tid, r = f >> 3, c = f & 7;
            *(i32x4*)&As[r * 64 + ((c * 8) ^ ((r & 7) << 3))] =
                *(const i32x4*)(Ag + (size_t)r * 512 + kt * 64 + c * 8);
            *(i32x4*)&Bs[r * 64 + ((c * 8) ^ ((r & 7) << 3))] =
                *(const i32x4*)(Bg + (size_t)r * 512 + kt * 64 + c * 8);
        }
        __syncthreads();
#pragma unroll
        for (int ks = 0; ks < 2; ks++) {
            s16x8 af[4], bf[4];
#pragma unroll
            for (int mf = 0; mf < 4; mf++) {
                int r = wr + mf * 16 + lr;
                af[mf] = *(const s16x8*)&As[r * 64 + ((ks * 32 + lg * 8) ^ ((r & 7) << 3))];
            }
#pragma unroll
            for (int nf = 0; nf < 4; nf++) {
                int r = wc + nf * 16 + lr;
                bf[nf] = *(const s16x8*)&Bs[r * 64 + ((ks * 32 + lg * 8) ^ ((r & 7) << 3))];
            }
#pragma unroll
            for (int mf = 0; mf < 4; mf++)
#pragma unroll
                for (int nf = 0; nf < 4; nf++)
                    acc[mf][nf] = __builtin_amdgcn_mfma_f32_16x16x32_bf16(
                        af[mf], bf[nf], acc[mf][nf], 0, 0, 0);
        }
    }
#pragma unroll
    for (int nf = 0; nf < 4; nf++) {
        int col = nblk * 128 + wc + nf * 16 + lr;
        float bval = bias[col];
#pragma unroll
        for (int mf = 0; mf < 4; mf++) {
#pragma unroll
            for (int r = 0; r < 4; r++) {
                int row = mblk * 128 + wr + mf * 16 + lg * 4 + r;
                float v = acc[mf][nf][r] + bval;
                if (F32OUT) Cf[(size_t)row * 512 + col] = v;
                else        Cb[(size_t)z * 2097152 + (size_t)row * 512 + col] = f2b(v);
            }
        }
    }
}

// ---------------- flash attention (swapped-QK 32x32, in-register softmax) ----
// grid (qt=16, h=8, b=2), 512 threads = 8 warps. Warp w: q rows (w&3)*32..+31,
// kv half (w>>2). S^T = mfma32x32(K, Q): lane owns q=l&31, regs own kv rows
// crow(r,hi)=(r&3)+8*(r>>2)+4*hi. Softmax in-register; cross-half exchange via
// __shfl_xor(·,32) (unambiguous semantics) + per-half selects. V transposed
// +swizzled in LDS, B-fragments via ds_read_b128. Defer-max THR=8. LDS merge.

__global__ __launch_bounds__(512)
void k_attn(const u16* __restrict__ qkv, const u32* __restrict__ mb,
            u16* __restrict__ oc) {
    const int qt = blockIdx.x, h = blockIdx.y, b = blockIdx.z;
    const u16* Qb = qkv + (size_t)b * 1048576 + h * 64;
    const u16* Kb = Qb + 2097152;
    const u16* Vb = Kb + 2097152;

    __shared__ __align__(16) u16 Ks[2][2][4096];   // [half][dbuf][64 rows][64] swizzled
    __shared__ __align__(16) u16 Vs[2][2][4096];   // [half][dbuf][e=64][kv=64] transposed+swizzled
    __shared__ float rscbuf[8][32];

    const int tid = threadIdx.x;
    const int lane = tid & 63, w = tid >> 6;
    const int hi = lane >> 5, l31 = lane & 31;
    const int qg = w & 3, half = w >> 2;
    const int qrow = qt * 128 + qg * 32 + l31;
    const int sr = tid >> 3, sc = tid & 7;

    // Q fragments (B-operand): qf[ks] = Q[qrow][ks*16 + hi*8 + j]
    s16x8 qf[4];
#pragma unroll
    for (int ks = 0; ks < 4; ks++)
        qf[ks] = *(const s16x8*)(Qb + (size_t)qrow * 512 + ks * 16 + hi * 8);

    const int kaddr = sr * 64 + ((sc * 8) ^ ((sr & 7) << 3));

    // prologue: stage tile 0 of both halves
    {
        i32x4 ka = *(const i32x4*)(Kb + (size_t)sr * 512 + sc * 8);
        i32x4 kb2 = *(const i32x4*)(Kb + (size_t)(1024 + sr) * 512 + sc * 8);
        i32x4 va = *(const i32x4*)(Vb + (size_t)sr * 512 + sc * 8);
        i32x4 vb2 = *(const i32x4*)(Vb + (size_t)(1024 + sr) * 512 + sc * 8);
        *(i32x4*)&Ks[0][0][kaddr] = ka;
        *(i32x4*)&Ks[1][0][kaddr] = kb2;
        union { i32x4 v; u16 u[8]; } ua, ub;
        ua.v = va; ub.v = vb2;
#pragma unroll
        for (int j = 0; j < 8; j++) {
            const int addr = (sc * 8 + j) * 64 + (sr ^ (((j ^ sc) & 7) << 3));
            Vs[0][0][addr] = ua.u[j];
            Vs[1][0][addr] = ub.u[j];
        }
    }
    u64 mreg = *(const u64*)(mb + ((size_t)b * 2048 + qrow) * 64 + half * 32);
    __syncthreads();

    f32x16 accO0 = zero16(), accO1 = zero16();
    f32x4 lvec = (f32x4){0.f, 0.f, 0.f, 0.f};
    float m_run = -3.0e38f;
    const float SC = 0.18033688011112042f;   // (1/8) * log2(e)

    for (int i = 0; i < 16; i++) {
        const int cur = i & 1;
        i32x4 kA, vA, kB, vB; u64 mnx = 0;
        if (i < 15) {
            kA = *(const i32x4*)(Kb + (size_t)((i + 1) * 64 + sr) * 512 + sc * 8);
            vA = *(const i32x4*)(Vb + (size_t)((i + 1) * 64 + sr) * 512 + sc * 8);
            kB = *(const i32x4*)(Kb + (size_t)(1024 + (i + 1) * 64 + sr) * 512 + sc * 8);
            vB = *(const i32x4*)(Vb + (size_t)(1024 + (i + 1) * 64 + sr) * 512 + sc * 8);
            mnx = *(const u64*)(mb + ((size_t)b * 2048 + qrow) * 64 + half * 32 + (i + 1) * 2);
        }

        // ---- QK^T (swapped): S^T[kv][q] = K_tile * Q^T ----
        const u16* KH = &Ks[half][cur][0];
        f32x16 sa0 = zero16(), sa1 = zero16();
#pragma unroll
        for (int ks = 0; ks < 4; ks++) {
            const int cb = ks * 16 + hi * 8;
            const int r0 = l31, r1 = 32 + l31;
            s16x8 kf0 = *(const s16x8*)&KH[r0 * 64 + (cb ^ ((r0 & 7) << 3))];
            s16x8 kf1 = *(const s16x8*)&KH[r1 * 64 + (cb ^ ((r0 & 7) << 3))];
            sa0 = __builtin_amdgcn_mfma_f32_32x32x16_bf16(kf0, qf[ks], sa0, 0, 0, 0);
            sa1 = __builtin_amdgcn_mfma_f32_32x32x16_bf16(kf1, qf[ks], sa1, 0, 0, 0);
        }
        f32x16 t0 = sa0 * SC, t1 = sa1 * SC;

        // ---- per-q max over all 64 kv (in-lane tree + cross-half shfl) ----
        float pm;
        {
            float mx[8];
#pragma unroll
            for (int j = 0; j < 8; j++)
                mx[j] = fmaxf(fmaxf(t0[j], t0[j + 8]), fmaxf(t1[j], t1[j + 8]));
#pragma unroll
            for (int s = 4; s > 0; s >>= 1)
#pragma unroll
                for (int j = 0; j < s; j++) mx[j] = fmaxf(mx[j], mx[j + s]);
            pm = fmaxf(mx[0], __shfl_xor(mx[0], 32, 64));
        }

        // ---- deferred rescale (T13, THR=8) ----
        if (__ballot(pm > m_run + 8.0f)) {
            float mn = fmaxf(m_run, pm);
            float rs = __builtin_amdgcn_exp2f(m_run - mn);
            m_run = mn;
            lvec *= rs;
            if (lane < 32) rscbuf[w][lane] = rs;
#pragma unroll
            for (int r = 0; r < 16; r++) {
                float rf = rscbuf[w][(r & 3) + 8 * (r >> 2) + 4 * hi];
                accO0[r] *= rf; accO1[r] *= rf;
            }
        }

        // ---- p = exp2(t - m) (in place), masked -> 0; accumulate row sums ----
        const u32 w0 = ((u32)mreg) >> (hi * 4);
        const u32 w1 = ((u32)(mreg >> 32)) >> (hi * 4);
#pragma unroll
        for (int r = 0; r < 16; r++) {
            const int pos = (r & 3) + 8 * (r >> 2);
            float e0 = __builtin_amdgcn_exp2f(t0[r] - m_run);
            float e1 = __builtin_amdgcn_exp2f(t1[r] - m_run);
            t0[r] = ((w0 >> pos) & 1u) ? 0.f : e0;
            t1[r] = ((w1 >> pos) & 1u) ? 0.f : e1;
            lvec[r & 3] += t0[r] + t1[r];
        }

        // ---- pack P to bf16; cross-half exchange via shfl_xor(·,32) ----
        // hi=0 lane holds kv pairs {0,1},{2,3},{8,9},{10,11},{16..},{24..} in pk0,
        // hi=1 same +4. A-frag pa[g] needs kv = g*16 + hi*8 + [0..7].
        u32 pk0[8], pk1[8];
#pragma unroll
        for (int g = 0; g < 8; g++) {
            pk0[g] = (u32)f2b(t0[2 * g]) | ((u32)f2b(t0[2 * g + 1]) << 16);
            pk1[g] = (u32)f2b(t1[2 * g]) | ((u32)f2b(t1[2 * g + 1]) << 16);
        }
        s16x8 pa[4];
        {
            u32 x0 = sx32(pk0[0]), x1 = sx32(pk0[1]), x2 = sx32(pk0[2]), x3 = sx32(pk0[3]);
            u32 x4 = sx32(pk0[4]), x5 = sx32(pk0[5]), x6 = sx32(pk0[6]), x7 = sx32(pk0[7]);
            pa[0] = mk8(hi ? x2 : pk0[0], hi ? x3 : pk0[1],
                        hi ? pk0[2] : x0, hi ? pk0[3] : x1);
            pa[1] = mk8(hi ? x6 : pk0[4], hi ? x7 : pk0[5],
                        hi ? pk0[6] : x4, hi ? pk0[7] : x5);
        }
        {
            u32 x0 = sx32(pk1[0]), x1 = sx32(pk1[1]), x2 = sx32(pk1[2]), x3 = sx32(pk1[3]);
            u32 x4 = sx32(pk1[4]), x5 = sx32(pk1[5]), x6 = sx32(pk1[6]), x7 = sx32(pk1[7]);
            pa[2] = mk8(hi ? x2 : pk1[0], hi ? x3 : pk1[1],
                        hi ? pk1[2] : x0, hi ? pk1[3] : x1);
            pa[3] = mk8(hi ? x6 : pk1[4], hi ? x7 : pk1[5],
                        hi ? pk1[6] : x4, hi ? pk1[7] : x5);
        }

        // ---- PV: accO[et] += P * V, V B-fragments from transposed LDS ----
        const u16* VH = &Vs[half][cur][0];
        const int e0 = l31, e1 = 32 + l31;
        const int sw0 = (((e0 & 7) ^ (e0 >> 3)) << 3);
        const int sw1 = (((e1 & 7) ^ ((e1 >> 3) & 7)) << 3);
#pragma unroll
        for (int ksg = 0; ksg < 4; ksg++) {
            const int cb = ksg * 16 + hi * 8;
            s16x8 bv0 = *(const s16x8*)&VH[e0 * 64 + (cb ^ sw0)];
            s16x8 bv1 = *(const s16x8*)&VH[e1 * 64 + (cb ^ sw1)];
            accO0 = __builtin_amdgcn_mfma_f32_32x32x16_bf16(pa[ksg], bv0, accO0, 0, 0, 0);
            accO1 = __builtin_amdgcn_mfma_f32_32x32x16_bf16(pa[ksg], bv1, accO1, 0, 0, 0);
        }

        // ---- stage tile i+1 into the other buffers ----
        __syncthreads();
        if (i < 15) {
            const int nb = cur ^ 1;
            *(i32x4*)&Ks[0][nb][kaddr] = kA;
            *(i32x4*)&Ks[1][nb][kaddr] = kB;
            union { i32x4 v; u16 u[8]; } ua, ub;
            ua.v = vA; ub.v = vB;
#pragma unroll
            for (int j = 0; j < 8; j++) {
                const int addr = (sc * 8 + j) * 64 + (sr ^ (((j ^ sc) & 7) << 3));
                Vs[0][nb][addr] = ua.u[j];
                Vs[1][nb][addr] = ub.u[j];
            }
            mreg = mnx;
        }
        __syncthreads();
    }

    // ---- finalize row sum within this kv half ----
    float Ls = (lvec[0] + lvec[1]) + (lvec[2] + lvec[3]);
    Ls += __shfl_xor(Ls, 32, 64);

    // ---- merge the two kv halves via LDS ----
    __syncthreads();
    float* fls = (float*)&Ks[0][0][0];       // 8192 floats: 4 warps x 2048
    float* mlb = (float*)&Vs[0][0][0];       // [4][32][2] m,l
    float* gbuf = mlb + 256;                 // [4][32][2] gA,gB
    const int xorv = (lane & 7) * 4;
    if (half == 1) {
        const int base = (w - 4) * 2048 + lane * 32;
#pragma unroll
        for (int r4 = 0; r4 < 4; r4++) {
            *(f32x4*)&fls[base + ((r4 * 4) ^ xorv)] =
                (f32x4){accO0[r4 * 4], accO0[r4 * 4 + 1], accO0[r4 * 4 + 2], accO0[r4 * 4 + 3]};
            *(f32x4*)&fls[base + ((16 + r4 * 4) ^ xorv)] =
                (f32x4){accO1[r4 * 4], accO1[r4 * 4 + 1], accO1[r4 * 4 + 2], accO1[r4 * 4 + 3]};
        }
        if (lane < 32) {
            mlb[(w - 4) * 64 + lane * 2] = m_run;
            mlb[(w - 4) * 64 + lane * 2 + 1] = Ls;
        }
    }
    __syncthreads();
    if (half == 0) {
        const float m_p = mlb[w * 64 + l31 * 2], L_p = mlb[w * 64 + l31 * 2 + 1];
        const float M = fmaxf(m_run, m_p);
        const float fA = __builtin_amdgcn_exp2f(m_run - M);
        const float fB = __builtin_amdgcn_exp2f(m_p - M);
        const float D = Ls * fA + L_p * fB;
        const float gA = fA / D, gB = fB / D;
        if (lane < 32) {
            gbuf[w * 64 + lane * 2] = gA;
            gbuf[w * 64 + lane * 2 + 1] = gB;
        }
        const int base = w * 2048 + lane * 32;
#pragma unroll
        for (int r4 = 0; r4 < 4; r4++) {
            f32x4 ap0 = *(const f32x4*)&fls[base + ((r4 * 4) ^ xorv)];
            f32x4 ap1 = *(const f32x4*)&fls[base + ((16 + r4 * 4) ^ xorv)];
#pragma unroll
            for (int j = 0; j < 4; j++) {
                const int r = r4 * 4 + j;
                const int qr = (r & 3) + 8 * (r >> 2) + 4 * hi;
                const float ga = gbuf[w * 64 + qr * 2], gb2 = gbuf[w * 64 + qr * 2 + 1];
                const size_t orow = (size_t)(b * 2048 + qt * 128 + qg * 32 + qr) * 512 + h * 64;
                oc[orow + l31]      = f2b(accO0[r] * ga + ap0[j] * gb2);
                oc[orow + 32 + l31] = f2b(accO1[r] * ga + ap1[j] * gb2);
            }
        }
    }
}

// ---------------- launcher ----------------

extern "C" void kernel_launch(void* const* d_in, const int* in_sizes, int n_in,
                              void* d_out, int out_size, void* d_ws, size_t ws_size,
                              hipStream_t stream) {
    const float* x    = (const float*)d_in[0];
    const int*   mask = (const int*)d_in[1];
    const float* Wq   = (const float*)d_in[2];
    const float* bq   = (const float*)d_in[3];
    const float* Wk   = (const float*)d_in[4];
    const float* bk   = (const float*)d_in[5];
    const float* Wv   = (const float*)d_in[6];
    const float* bv   = (const float*)d_in[7];
    const float* Wo   = (const float*)d_in[8];
    const float* bo   = (const float*)d_in[9];

    u16* xb     = (u16*)d_ws;              // 2097152 bf16
    u16* WT     = xb + 2097152;            // 3*262144
    u16* WoT    = WT + 786432;             // 262144
    u16* qkv    = WoT + 262144;            // 3*2097152
    u16* oc     = qkv + 6291456;           // 2097152
    float* bias = (float*)(oc + 2097152);  // 2048 floats
    unsigned* mbits = (unsigned*)(bias + 2048); // 262144 words (1 MB)

    k_cvt_x     <<<2048, 256, 0, stream>>>(x, xb);
    k_pack_w    <<<1024, 256, 0, stream>>>(Wq, WT);
    k_pack_w    <<<1024, 256, 0, stream>>>(Wk, WT + 262144);
    k_pack_w    <<<1024, 256, 0, stream>>>(Wv, WT + 524288);
    k_pack_wo   <<<1024, 256, 0, stream>>>(Wo, WoT);
    k_pack_bias <<<8, 256, 0, stream>>>(bq, bk, bv, bo, bias);
    k_pack_mbits<<<1024, 256, 0, stream>>>(mask, mbits);

    k_gemm<false><<<dim3(4, 32, 3), 256, 0, stream>>>(xb, WT, bias, qkv, nullptr);
    k_attn<<<dim3(16, 8, 2), 512, 0, stream>>>(qkv, mbits, oc);
    k_gemm<true><<<dim3(4, 32, 1), 256, 0, stream>>>(oc, WoT, bias + 1536, nullptr, (float*)d_out);
}